// Round 6
// baseline (7411.872 us; speedup 1.0000x reference)
//
#include <hip/hip_runtime.h>
#include <cmath>

#define B_ 64
#define S_ 1024
#define I_ 512
#define H_ 1024
#define O_ 512
#define HB (H_ * B_)   // 65536
#define SCAN_NBLK 64
#define PROD_NBLK 96
#define WORK_NBLK 96
#define NTHR 512
#define NPROD_PER_S 8   // inproj h-tiles of 128 per s
#define SPIN_BUDGET (1 << 22)

typedef __attribute__((ext_vector_type(8))) __bf16 bf16x8;
typedef __attribute__((ext_vector_type(4))) float f32x4;
typedef unsigned long long u64;

// frag layout for mfma_f32_16x16x32_bf16 B-operand: lane holds
// B[k = (lane>>4)*8 + j][n = lane&15]; tiles: kt = k>>5 (32 tiles), nt = b>>4 (4).
__device__ __forceinline__ int fragIdx(int k, int b) {
  int kt = k >> 5, q = (k >> 3) & 3, slot = k & 7;
  int nt = b >> 4, ln = q * 16 + (b & 15);
  return (((kt * 4 + nt) * 64) + ln) * 8 + slot;
}

// ---------------------------------------------------------------------------
// h0 (B,H) fp32 -> initial B-fragment arrays (hi/lo bf16 split)
// ---------------------------------------------------------------------------
__global__ void k_hfrag0(const float* __restrict__ h0,
                         unsigned short* __restrict__ hh,
                         unsigned short* __restrict__ hl) {
  int idx = blockIdx.x * 256 + threadIdx.x;  // 65536
  int b = idx >> 10, k = idx & 1023;
  float v = h0[(size_t)b * H_ + k];
  __bf16 h = (__bf16)v;
  __bf16 l = (__bf16)(v - (float)h);
  int fi = fragIdx(k, b);
  hh[fi] = __builtin_bit_cast(unsigned short, h);
  hl[fi] = __builtin_bit_cast(unsigned short, l);
}

// ---------------------------------------------------------------------------
// Fully fused persistent kernel, 256 blocks x 512 threads (round-4 proven
// structure):
//   blocks [0,64)    : recurrent scan
//   blocks [64,160)  : inproj producers -> xp[s] (agent sc1), signal incnt[s]
//   blocks [160,256) : outproj workers, gated on aggregated done counter
// Round-6 changes vs round-4 (scan only):
//   (a) all 32 frag b128 loads hoisted to step top into uint4 F[32]
//       (batched IF$ latency: 1 wait instead of 4 serialized) ~128 VGPR
//   (b) wave-0 acquire fence moved BEFORE drain-syncthreads (inv overlaps
//       the publish drain; dbuf + bypass-only loads in between keep it safe)
//   (c) spin budgets everywhere (graceful numeric failure, never a hang)
// bar map: [0..63] scan flags | [128] dn | [256..1279] incnt[S_]
// ---------------------------------------------------------------------------
__global__ __launch_bounds__(NTHR) void k_fused(
    const float* __restrict__ Whh, float* __restrict__ xp,
    unsigned short* __restrict__ hh0, unsigned short* __restrict__ hl0,
    unsigned short* __restrict__ hh1, unsigned short* __restrict__ hl1,
    unsigned* __restrict__ bar,
    const float* __restrict__ Who, const float* __restrict__ bho,
    float* __restrict__ out,
    const float* __restrict__ x, const float* __restrict__ Wih,
    const float* __restrict__ bih, const float* __restrict__ bhh) {
  __shared__ float sh[9216];   // 36 KB union
  const int t = threadIdx.x;
  unsigned* dn    = bar + 128;
  unsigned* incnt = bar + 256;
  int budget = SPIN_BUDGET;

  if (blockIdx.x < SCAN_NBLK) {
    // ============================ SCAN ============================
    float* red  = sh;          // [w][nt][lane][reg] : 8*4*64*4 floats
    float* hbuf = sh + 8192;   // [j][b] : 16*64
    const int lane = t & 63;
    const int w    = t >> 6;          // wave 0..7: k-slice [w*128, w*128+128)
    const int j0   = blockIdx.x * 16;
    const int m    = lane & 15, q = lane >> 4;

    // ---- one-time: W A-fragments, fp32 -> bf16 hi+lo split ----
    bf16x8 Ahi[4], Alo[4];
    #pragma unroll
    for (int kta = 0; kta < 4; kta++) {
      const float* src = Whh + (size_t)(j0 + m) * H_ + (w * 128 + kta * 32 + q * 8);
      float4 v0 = *(const float4*)src;
      float4 v1 = *(const float4*)(src + 4);
      float vv[8] = {v0.x, v0.y, v0.z, v0.w, v1.x, v1.y, v1.z, v1.w};
      #pragma unroll
      for (int j = 0; j < 8; j++) {
        __bf16 h = (__bf16)vv[j];
        __bf16 l = (__bf16)(vv[j] - (float)h);
        Ahi[kta][j] = h;
        Alo[kta][j] = l;
      }
    }

    // xp register prefetch state (per-thread fixed addresses)
    const int jA = t >> 6, bA = t & 63;
    const size_t xi0 = (size_t)(j0 + jA) * 64 + bA;       // rep 0
    const size_t xi1 = (size_t)(j0 + 8 + jA) * 64 + bA;   // rep 1

    // gate on producers for xp[0] (launch-fresh caches -> plain loads ok)
    while (__hip_atomic_load(&incnt[0], __ATOMIC_RELAXED,
                             __HIP_MEMORY_SCOPE_AGENT) < NPROD_PER_S) {
      if (--budget < 0) break;
      __builtin_amdgcn_s_sleep(16);
    }
    asm volatile("" ::: "memory");
    float xc0 = xp[xi0];
    float xc1 = xp[xi1];

    const unsigned short* rdh = hh0;
    const unsigned short* rdl = hl0;
    unsigned short* wrh = hh1;
    unsigned short* wrl = hl1;

    for (int s = 0; s < S_; s++) {
      // ---- (a) hoisted frag loads: all 32 b128 issued before any MFMA ----
      uint4 F[32];
      #pragma unroll
      for (int kta = 0; kta < 4; kta++) {
        const int ktg = w * 4 + kta;
        const unsigned short* ph = rdh + ((size_t)(ktg * 4) * 64 + lane) * 8;
        const unsigned short* pl = rdl + ((size_t)(ktg * 4) * 64 + lane) * 8;
        #pragma unroll
        for (int i = 0; i < 4; i++) {
          F[kta * 8 + i]     = *(const uint4*)(ph + i * 512);
          F[kta * 8 + 4 + i] = *(const uint4*)(pl + i * 512);
        }
      }
      f32x4 acc0 = 0.f, acc1 = 0.f, acc2 = 0.f, acc3 = 0.f;
      #pragma unroll
      for (int kta = 0; kta < 4; kta++) {
        bf16x8 bh0 = __builtin_bit_cast(bf16x8, F[kta * 8 + 0]);
        bf16x8 bh1 = __builtin_bit_cast(bf16x8, F[kta * 8 + 1]);
        bf16x8 bh2 = __builtin_bit_cast(bf16x8, F[kta * 8 + 2]);
        bf16x8 bh3 = __builtin_bit_cast(bf16x8, F[kta * 8 + 3]);
        bf16x8 bl0 = __builtin_bit_cast(bf16x8, F[kta * 8 + 4]);
        bf16x8 bl1 = __builtin_bit_cast(bf16x8, F[kta * 8 + 5]);
        bf16x8 bl2 = __builtin_bit_cast(bf16x8, F[kta * 8 + 6]);
        bf16x8 bl3 = __builtin_bit_cast(bf16x8, F[kta * 8 + 7]);
        acc0 = __builtin_amdgcn_mfma_f32_16x16x32_bf16(Ahi[kta], bh0, acc0, 0, 0, 0);
        acc1 = __builtin_amdgcn_mfma_f32_16x16x32_bf16(Ahi[kta], bh1, acc1, 0, 0, 0);
        acc2 = __builtin_amdgcn_mfma_f32_16x16x32_bf16(Ahi[kta], bh2, acc2, 0, 0, 0);
        acc3 = __builtin_amdgcn_mfma_f32_16x16x32_bf16(Ahi[kta], bh3, acc3, 0, 0, 0);
        acc0 = __builtin_amdgcn_mfma_f32_16x16x32_bf16(Alo[kta], bh0, acc0, 0, 0, 0);
        acc1 = __builtin_amdgcn_mfma_f32_16x16x32_bf16(Alo[kta], bh1, acc1, 0, 0, 0);
        acc2 = __builtin_amdgcn_mfma_f32_16x16x32_bf16(Alo[kta], bh2, acc2, 0, 0, 0);
        acc3 = __builtin_amdgcn_mfma_f32_16x16x32_bf16(Alo[kta], bh3, acc3, 0, 0, 0);
        acc0 = __builtin_amdgcn_mfma_f32_16x16x32_bf16(Ahi[kta], bl0, acc0, 0, 0, 0);
        acc1 = __builtin_amdgcn_mfma_f32_16x16x32_bf16(Ahi[kta], bl1, acc1, 0, 0, 0);
        acc2 = __builtin_amdgcn_mfma_f32_16x16x32_bf16(Ahi[kta], bl2, acc2, 0, 0, 0);
        acc3 = __builtin_amdgcn_mfma_f32_16x16x32_bf16(Ahi[kta], bl3, acc3, 0, 0, 0);
      }
      // ---- cross-wave reduce via LDS ----
      *(f32x4*)&red[(((w * 4 + 0) * 64) + lane) * 4] = acc0;
      *(f32x4*)&red[(((w * 4 + 1) * 64) + lane) * 4] = acc1;
      *(f32x4*)&red[(((w * 4 + 2) * 64) + lane) * 4] = acc2;
      *(f32x4*)&red[(((w * 4 + 3) * 64) + lane) * 4] = acc3;
      __syncthreads();
      float* hcur = xp + (size_t)s * HB;
      #pragma unroll
      for (int rep = 0; rep < 2; rep++) {
        const int j = jA + rep * 8, b = bA;
        const int nt = b >> 4, lc = (j >> 2) * 16 + (b & 15), reg = j & 3;
        float sum = 0.f;
        #pragma unroll
        for (int ww = 0; ww < 8; ww++)
          sum += red[(((ww * 4 + nt) * 64) + lc) * 4 + reg];
        const size_t xi = (rep == 0) ? xi0 : xi1;
        const float xv = (rep == 0) ? xc0 : xc1;
        float v = tanhf(xv + sum);
        // fp32 h published coherently (workers on other XCDs consume it)
        __hip_atomic_store(&hcur[xi], v, __ATOMIC_RELAXED, __HIP_MEMORY_SCOPE_AGENT);
        hbuf[j * 64 + b] = v;
      }
      __syncthreads();
      // ---- coalesced frag publish: 128 threads x (2+2) u64 sc1 stores ----
      if (t < 128) {
        const int jg = t >> 6, b = t & 63;
        const int k0 = j0 + jg * 8;           // 8 consecutive k, k0 % 8 == 0
        const int kt = k0 >> 5, qq = (k0 >> 3) & 3;
        const int nt = b >> 4, ln = qq * 16 + (b & 15);
        const size_t fb = ((size_t)((kt * 4 + nt) * 64 + ln)) * 8;
        unsigned hu[8], lu[8];
        #pragma unroll
        for (int jj = 0; jj < 8; jj++) {
          float v = hbuf[(jg * 8 + jj) * 64 + b];
          __bf16 hh = (__bf16)v;
          __bf16 ll = (__bf16)(v - (float)hh);
          hu[jj] = (unsigned)__builtin_bit_cast(unsigned short, hh);
          lu[jj] = (unsigned)__builtin_bit_cast(unsigned short, ll);
        }
        u64 hw0 = (u64)hu[0] | ((u64)hu[1] << 16) | ((u64)hu[2] << 32) | ((u64)hu[3] << 48);
        u64 hw1 = (u64)hu[4] | ((u64)hu[5] << 16) | ((u64)hu[6] << 32) | ((u64)hu[7] << 48);
        u64 lw0 = (u64)lu[0] | ((u64)lu[1] << 16) | ((u64)lu[2] << 32) | ((u64)lu[3] << 48);
        u64 lw1 = (u64)lu[4] | ((u64)lu[5] << 16) | ((u64)lu[6] << 32) | ((u64)lu[7] << 48);
        __hip_atomic_store((u64*)(wrh + fb) + 0, hw0, __ATOMIC_RELAXED, __HIP_MEMORY_SCOPE_AGENT);
        __hip_atomic_store((u64*)(wrh + fb) + 1, hw1, __ATOMIC_RELAXED, __HIP_MEMORY_SCOPE_AGENT);
        __hip_atomic_store((u64*)(wrl + fb) + 0, lw0, __ATOMIC_RELAXED, __HIP_MEMORY_SCOPE_AGENT);
        __hip_atomic_store((u64*)(wrl + fb) + 1, lw1, __ATOMIC_RELAXED, __HIP_MEMORY_SCOPE_AGENT);
      }
      // (b) acquire fence EARLY: buffer_inv overlaps the publish drain.
      // Safe: dbuf means next-step lines are never refilled before the gated
      // loads (only bypassing atomics + unrelated addresses touched between).
      if (t < 64) __builtin_amdgcn_fence(__ATOMIC_ACQUIRE, "agent");
      __syncthreads();   // drains vmcnt -> all sc1 stores at IF$ before flag
      if (t == 0)
        __hip_atomic_store(&bar[blockIdx.x], (unsigned)(s + 1),
                           __ATOMIC_RELAXED, __HIP_MEMORY_SCOPE_AGENT);
      const int sn = s + 1;
      const float* xpn = xp + (size_t)sn * HB;
      if (t >= 64) {
        // waves 1..7: gated prefetch of next xp slice into regs
        if (sn < S_) {
          while (__hip_atomic_load(&incnt[sn], __ATOMIC_RELAXED,
                                   __HIP_MEMORY_SCOPE_AGENT) < NPROD_PER_S) {
            if (--budget < 0) break;
            __builtin_amdgcn_s_sleep(1);
          }
          asm volatile("" ::: "memory");
          xc0 = xpn[xi0]; xc1 = xpn[xi1];
        }
      } else {
        if (sn < S_) {
          while (__hip_atomic_load(&incnt[sn], __ATOMIC_RELAXED,
                                   __HIP_MEMORY_SCOPE_AGENT) < NPROD_PER_S) {
            if (--budget < 0) break;
            __builtin_amdgcn_s_sleep(1);
          }
          asm volatile("" ::: "memory");
          xc0 = xpn[xi0]; xc1 = xpn[xi1];
        }
        const unsigned need = (unsigned)sn;
        while (__hip_atomic_load(&bar[lane], __ATOMIC_RELAXED,
                                 __HIP_MEMORY_SCOPE_AGENT) < need) {
          if (--budget < 0) break;
          __builtin_amdgcn_s_sleep(1);
        }
        if (t == 0 && blockIdx.x == 0)
          __hip_atomic_store(dn, (unsigned)sn,
                             __ATOMIC_RELAXED, __HIP_MEMORY_SCOPE_AGENT);
      }
      __syncthreads();
      // swap double buffers
      const unsigned short* th = rdh; rdh = wrh; wrh = (unsigned short*)th;
      const unsigned short* tl = rdl; rdl = wrl; wrl = (unsigned short*)tl;
    }
  } else if (blockIdx.x < SCAN_NBLK + PROD_NBLK) {
    // ======================== INPROJ PRODUCERS ========================
    // item = s*8 + htile(128): xp[s][h][b] = sum_i x[b][s][i]*Wih[h][i]+bih+bhh
    float* As = sh;              // [128][36] Wih tile (h x k)
    float* Bs = sh + 128 * 36;   // [32][72]  x tile   (k x b)
    const int pid = blockIdx.x - SCAN_NBLK;
    const int tx = t & 15, ty = t >> 4;        // b-quad, h-quad (32 rows)
    const int bS = t >> 3, c4S = (t & 7) * 4;  // Bs staging coords
    for (int item = pid; item < S_ * 8; item += PROD_NBLK) {
      const int s = item >> 3, h00 = (item & 7) << 7;
      float acc[4][4] = {};
      for (int k0 = 0; k0 < I_; k0 += 32) {
        #pragma unroll
        for (int L = 0; L < 2; L++) {
          int f = L * 512 + t;
          int row = f >> 3, c4 = (f & 7) * 4;
          float4 v = *(const float4*)&Wih[(size_t)(h00 + row) * I_ + k0 + c4];
          *(float4*)&As[row * 36 + c4] = v;
        }
        {
          float4 v = *(const float4*)&x[(size_t)bS * (S_ * I_) + (size_t)s * I_ + k0 + c4S];
          Bs[(c4S + 0) * 72 + bS] = v.x;
          Bs[(c4S + 1) * 72 + bS] = v.y;
          Bs[(c4S + 2) * 72 + bS] = v.z;
          Bs[(c4S + 3) * 72 + bS] = v.w;
        }
        __syncthreads();
        #pragma unroll
        for (int k = 0; k < 32; k += 4) {
          float4 a[4], bq[4];
          #pragma unroll
          for (int r = 0; r < 4; r++) a[r] = *(const float4*)&As[(ty * 4 + r) * 36 + k];
          #pragma unroll
          for (int kk = 0; kk < 4; kk++) bq[kk] = *(const float4*)&Bs[(k + kk) * 72 + tx * 4];
          #pragma unroll
          for (int kk = 0; kk < 4; kk++)
            #pragma unroll
            for (int r = 0; r < 4; r++)
              #pragma unroll
              for (int c = 0; c < 4; c++)
                acc[r][c] += ((const float*)&a[r])[kk] * ((const float*)&bq[kk])[c];
        }
        __syncthreads();
      }
      #pragma unroll
      for (int r = 0; r < 4; r++) {
        const int h = h00 + ty * 4 + r;
        const float bias = bih[h] + bhh[h];
        float2 p0 = {acc[r][0] + bias, acc[r][1] + bias};
        float2 p1 = {acc[r][2] + bias, acc[r][3] + bias};
        u64* dst = (u64*)&xp[(size_t)s * HB + (size_t)h * 64 + tx * 4];
        __hip_atomic_store(dst + 0, __builtin_bit_cast(u64, p0),
                           __ATOMIC_RELAXED, __HIP_MEMORY_SCOPE_AGENT);
        __hip_atomic_store(dst + 1, __builtin_bit_cast(u64, p1),
                           __ATOMIC_RELAXED, __HIP_MEMORY_SCOPE_AGENT);
      }
      __syncthreads();   // drains vmcnt in every wave -> stores at IF$
      if (t == 0)
        __hip_atomic_fetch_add(&incnt[s], 1u,
                               __ATOMIC_RELAXED, __HIP_MEMORY_SCOPE_AGENT);
    }
  } else {
    // ======================== OUTPROJ WORKERS ========================
    // item = s*4 + otile(128): out[b][s][o] = sum_h hs[s][h][b]*Who[o][h]+bho
    float* As = sh;              // [32][68]  hs tile  (k x b)
    float* Bs = sh + 32 * 68;    // [32][132] Who tile (k x o)
    const int wid = blockIdx.x - SCAN_NBLK - PROD_NBLK;
    const int tx = t & 31, ty = t >> 5;          // o-quad (32), b-quad (16)
    const int kkA = t >> 4, b4 = (t & 15) * 4;   // As staging coords
    for (int item = wid; item < S_ * 4; item += WORK_NBLK) {
      const int s = item >> 2, o0 = (item & 3) << 7;
      if (t == 0) {
        const unsigned need = (unsigned)(s + 1);
        while (__hip_atomic_load(dn, __ATOMIC_RELAXED,
                                 __HIP_MEMORY_SCOPE_AGENT) < need) {
          if (--budget < 0) break;
          __builtin_amdgcn_s_sleep(8);
        }
      }
      __syncthreads();
      const float* hsS = xp + (size_t)s * HB;
      float acc[4][4] = {};
      for (int k0 = 0; k0 < H_; k0 += 32) {
        // hs via agent-scope u64 loads: coherent from IF$, no cache inv needed
        const u64* hp = (const u64*)&hsS[(size_t)(k0 + kkA) * 64 + b4];
        u64 w0 = __hip_atomic_load(hp + 0, __ATOMIC_RELAXED, __HIP_MEMORY_SCOPE_AGENT);
        u64 w1 = __hip_atomic_load(hp + 1, __ATOMIC_RELAXED, __HIP_MEMORY_SCOPE_AGENT);
        *(float2*)&As[kkA * 68 + b4 + 0] = __builtin_bit_cast(float2, w0);
        *(float2*)&As[kkA * 68 + b4 + 2] = __builtin_bit_cast(float2, w1);
        #pragma unroll
        for (int L = 0; L < 2; L++) {
          int f = L * 512 + t;
          int row = f >> 3, c4 = (f & 7) * 4;    // row in [0,128) = o offset
          float4 v = *(const float4*)&Who[(size_t)(o0 + row) * H_ + k0 + c4];
          Bs[(c4 + 0) * 132 + row] = v.x;
          Bs[(c4 + 1) * 132 + row] = v.y;
          Bs[(c4 + 2) * 132 + row] = v.z;
          Bs[(c4 + 3) * 132 + row] = v.w;
        }
        __syncthreads();
        #pragma unroll
        for (int k = 0; k < 32; k++) {
          float4 a4 = *(const float4*)&As[k * 68 + ty * 4];
          float4 bq = *(const float4*)&Bs[k * 132 + tx * 4];
          #pragma unroll
          for (int r = 0; r < 4; r++)
            #pragma unroll
            for (int c = 0; c < 4; c++)
              acc[r][c] += ((const float*)&a4)[r] * ((const float*)&bq)[c];
        }
        __syncthreads();
      }
      #pragma unroll
      for (int r = 0; r < 4; r++) {
        const int b = ty * 4 + r;
        float4 o4;
        o4.x = acc[r][0] + bho[o0 + tx * 4 + 0];
        o4.y = acc[r][1] + bho[o0 + tx * 4 + 1];
        o4.z = acc[r][2] + bho[o0 + tx * 4 + 2];
        o4.w = acc[r][3] + bho[o0 + tx * 4 + 3];
        *(float4*)&out[(size_t)b * (S_ * O_) + (size_t)s * O_ + o0 + tx * 4] = o4;
      }
    }
  }
}

// last hidden: (H,B) slice -> out (B,H)
__global__ void k_lasth(const float* __restrict__ hlast, float* __restrict__ out) {
  int idx = blockIdx.x * 256 + threadIdx.x;  // 65536 total
  int b = idx >> 10, h = idx & 1023;
  out[idx] = hlast[h * 64 + b];
}

extern "C" void kernel_launch(void* const* d_in, const int* in_sizes, int n_in,
                              void* d_out, int out_size, void* d_ws, size_t ws_size,
                              hipStream_t stream) {
  const float* x    = (const float*)d_in[0];
  const float* h0   = (const float*)d_in[1];
  const float* Wih  = (const float*)d_in[2];
  const float* bih  = (const float*)d_in[3];
  const float* Whh  = (const float*)d_in[4];
  const float* bhh  = (const float*)d_in[5];
  const float* Who  = (const float*)d_in[6];
  const float* bho  = (const float*)d_in[7];
  float* out = (float*)d_out;

  // ws: xp/hs (S,H,B) fp32 = 268.4 MB | 4 frag arrays 128 KB | counters 8 KB
  float* xp = (float*)d_ws;
  unsigned short* hh0 = (unsigned short*)(xp + (size_t)S_ * HB);
  unsigned short* hl0 = hh0 + HB;
  unsigned short* hh1 = hl0 + HB;
  unsigned short* hl1 = hh1 + HB;
  unsigned* bar = (unsigned*)(hl1 + HB);   // flags | done(+128) | incnt(+256)

  hipMemsetAsync(bar, 0, 8192, stream);
  k_hfrag0<<<256, 256, 0, stream>>>(h0, hh0, hl0);

  void* args[] = {(void*)&Whh, (void*)&xp, (void*)&hh0, (void*)&hl0,
                  (void*)&hh1, (void*)&hl1, (void*)&bar,
                  (void*)&Who, (void*)&bho, (void*)&out,
                  (void*)&x, (void*)&Wih, (void*)&bih, (void*)&bhh};
  hipLaunchCooperativeKernel((const void*)k_fused,
                             dim3(SCAN_NBLK + PROD_NBLK + WORK_NBLK), dim3(NTHR),
                             args, 0, stream);

  k_lasth<<<256, 256, 0, stream>>>(xp + (size_t)(S_ - 1) * HB, out + (size_t)B_ * S_ * O_);
}

// Round 8
// 6196.391 us; speedup vs baseline: 1.1962x; 1.1962x over previous
//
#include <hip/hip_runtime.h>
#include <cmath>

#define B_ 64
#define S_ 1024
#define I_ 512
#define H_ 1024
#define O_ 512
#define HB (H_ * B_)   // 65536
#define SCAN_NBLK 32   // 32 blocks x 32 rows: halves per-step frag IF$ traffic
#define PROD_NBLK 112
#define WORK_NBLK 112
#define NTHR 512
#define NPROD_PER_S 8   // inproj h-tiles of 128 per s
#define SPIN_BUDGET (1 << 20)

typedef __attribute__((ext_vector_type(8))) __bf16 bf16x8;
typedef __attribute__((ext_vector_type(4))) float f32x4;
typedef unsigned long long u64;

// frag layout for mfma_f32_16x16x32_bf16 B-operand: lane holds
// B[k = (lane>>4)*8 + j][n = lane&15]; tiles: kt = k>>5 (32 tiles), nt = b>>4 (4).
__device__ __forceinline__ int fragIdx(int k, int b) {
  int kt = k >> 5, q = (k >> 3) & 3, slot = k & 7;
  int nt = b >> 4, ln = q * 16 + (b & 15);
  return (((kt * 4 + nt) * 64) + ln) * 8 + slot;
}

// ---------------------------------------------------------------------------
// h0 (B,H) fp32 -> initial B-fragment arrays (hi/lo bf16 split)
// ---------------------------------------------------------------------------
__global__ void k_hfrag0(const float* __restrict__ h0,
                         unsigned short* __restrict__ hh,
                         unsigned short* __restrict__ hl) {
  int idx = blockIdx.x * 256 + threadIdx.x;  // 65536
  int b = idx >> 10, k = idx & 1023;
  float v = h0[(size_t)b * H_ + k];
  __bf16 h = (__bf16)v;
  __bf16 l = (__bf16)(v - (float)h);
  int fi = fragIdx(k, b);
  hh[fi] = __builtin_bit_cast(unsigned short, h);
  hl[fi] = __builtin_bit_cast(unsigned short, l);
}

// ---------------------------------------------------------------------------
// Fully fused persistent kernel, 256 blocks x 512 threads:
//   blocks [0,32)    : recurrent scan, 32 rows each (2 m-tiles per wave)
//   blocks [32,144)  : inproj producers -> xp[s] (agent sc1), signal incnt[s]
//   blocks [144,256) : outproj workers, gated on aggregated done counter
// Coherence protocol = round-4 proven: sc1 write-through publish, per-step
// agent acquire fence (buffer_inv), plain b128 frag reads, per-block monotone
// flags, single aggregated done counter. Spin budgets everywhere (worst-case
// fall-through ~100 ms, then graceful numeric failure -- never a hang).
// bar map: [0..31] scan flags | [128] dn | [256..1279] incnt[S_]
// ---------------------------------------------------------------------------
__global__ __launch_bounds__(NTHR) void k_fused(
    const float* __restrict__ Whh, float* __restrict__ xp,
    unsigned short* __restrict__ hh0, unsigned short* __restrict__ hl0,
    unsigned short* __restrict__ hh1, unsigned short* __restrict__ hl1,
    unsigned* __restrict__ bar,
    const float* __restrict__ Who, const float* __restrict__ bho,
    float* __restrict__ out,
    const float* __restrict__ x, const float* __restrict__ Wih,
    const float* __restrict__ bih, const float* __restrict__ bhh) {
  __shared__ float sh[10240];   // 40 KB union: scan {red 8192, hbuf 2048}
  const int t = threadIdx.x;
  unsigned* dn    = bar + 128;
  unsigned* incnt = bar + 256;
  int budget = SPIN_BUDGET;

  if (blockIdx.x < SCAN_NBLK) {
    // ============================ SCAN ============================
    float* red  = sh;          // [w][i][lane][reg] : 8*4*64*4 floats
    float* hbuf = sh + 8192;   // [32 rows][64 b]
    const int lane = t & 63;
    const int w    = t >> 6;          // wave 0..7: k-slice [w*128, w*128+128)
    const int j0   = blockIdx.x * 32;
    const int m    = lane & 15, q = lane >> 4;

    // ---- one-time: W A-fragments (2 m-tiles), fp32 -> bf16 hi+lo split ----
    bf16x8 Ahi[2][4], Alo[2][4];
    #pragma unroll
    for (int mt = 0; mt < 2; mt++)
      #pragma unroll
      for (int kta = 0; kta < 4; kta++) {
        const float* src = Whh + (size_t)(j0 + mt * 16 + m) * H_ +
                           (w * 128 + kta * 32 + q * 8);
        float4 v0 = *(const float4*)src;
        float4 v1 = *(const float4*)(src + 4);
        float vv[8] = {v0.x, v0.y, v0.z, v0.w, v1.x, v1.y, v1.z, v1.w};
        #pragma unroll
        for (int j = 0; j < 8; j++) {
          __bf16 h = (__bf16)vv[j];
          __bf16 l = (__bf16)(vv[j] - (float)h);
          Ahi[mt][kta][j] = h;
          Alo[mt][kta][j] = l;
        }
      }

    // xp prefetch addresses: 4 outputs/thread, p = mt*2+rep
    const int jA = t >> 6, bA = t & 63;
    size_t xia[4];
    #pragma unroll
    for (int mt = 0; mt < 2; mt++)
      #pragma unroll
      for (int rep = 0; rep < 2; rep++)
        xia[mt * 2 + rep] = (size_t)(j0 + mt * 16 + jA + rep * 8) * 64 + bA;

    // gate on producers for xp[0] (launch-fresh caches -> plain loads ok)
    while (__hip_atomic_load(&incnt[0], __ATOMIC_RELAXED,
                             __HIP_MEMORY_SCOPE_AGENT) < NPROD_PER_S) {
      if (--budget < 0) break;
      __builtin_amdgcn_s_sleep(8);
    }
    asm volatile("" ::: "memory");
    float xc[4];
    #pragma unroll
    for (int p = 0; p < 4; p++) xc[p] = xp[xia[p]];

    const unsigned short* rdh = hh0;
    const unsigned short* rdl = hl0;
    unsigned short* wrh = hh1;
    unsigned short* wrl = hl1;

    for (int s = 0; s < S_; s++) {
      // ---- B-frag loads + MFMA: 96 MFMA, 32 b128 loads per wave ----
      f32x4 acc[2][4];
      #pragma unroll
      for (int mt = 0; mt < 2; mt++)
        #pragma unroll
        for (int i = 0; i < 4; i++) acc[mt][i] = 0.f;
      #pragma unroll
      for (int kta = 0; kta < 4; kta++) {
        const int ktg = w * 4 + kta;
        const unsigned short* ph = rdh + ((size_t)(ktg * 4) * 64 + lane) * 8;
        const unsigned short* pl = rdl + ((size_t)(ktg * 4) * 64 + lane) * 8;
        bf16x8 bh0 = __builtin_bit_cast(bf16x8, *(const uint4*)(ph + 0 * 512));
        bf16x8 bh1 = __builtin_bit_cast(bf16x8, *(const uint4*)(ph + 1 * 512));
        bf16x8 bh2 = __builtin_bit_cast(bf16x8, *(const uint4*)(ph + 2 * 512));
        bf16x8 bh3 = __builtin_bit_cast(bf16x8, *(const uint4*)(ph + 3 * 512));
        bf16x8 bl0 = __builtin_bit_cast(bf16x8, *(const uint4*)(pl + 0 * 512));
        bf16x8 bl1 = __builtin_bit_cast(bf16x8, *(const uint4*)(pl + 1 * 512));
        bf16x8 bl2 = __builtin_bit_cast(bf16x8, *(const uint4*)(pl + 2 * 512));
        bf16x8 bl3 = __builtin_bit_cast(bf16x8, *(const uint4*)(pl + 3 * 512));
        #pragma unroll
        for (int mt = 0; mt < 2; mt++) {
          acc[mt][0] = __builtin_amdgcn_mfma_f32_16x16x32_bf16(Ahi[mt][kta], bh0, acc[mt][0], 0, 0, 0);
          acc[mt][1] = __builtin_amdgcn_mfma_f32_16x16x32_bf16(Ahi[mt][kta], bh1, acc[mt][1], 0, 0, 0);
          acc[mt][2] = __builtin_amdgcn_mfma_f32_16x16x32_bf16(Ahi[mt][kta], bh2, acc[mt][2], 0, 0, 0);
          acc[mt][3] = __builtin_amdgcn_mfma_f32_16x16x32_bf16(Ahi[mt][kta], bh3, acc[mt][3], 0, 0, 0);
          acc[mt][0] = __builtin_amdgcn_mfma_f32_16x16x32_bf16(Alo[mt][kta], bh0, acc[mt][0], 0, 0, 0);
          acc[mt][1] = __builtin_amdgcn_mfma_f32_16x16x32_bf16(Alo[mt][kta], bh1, acc[mt][1], 0, 0, 0);
          acc[mt][2] = __builtin_amdgcn_mfma_f32_16x16x32_bf16(Alo[mt][kta], bh2, acc[mt][2], 0, 0, 0);
          acc[mt][3] = __builtin_amdgcn_mfma_f32_16x16x32_bf16(Alo[mt][kta], bh3, acc[mt][3], 0, 0, 0);
          acc[mt][0] = __builtin_amdgcn_mfma_f32_16x16x32_bf16(Ahi[mt][kta], bl0, acc[mt][0], 0, 0, 0);
          acc[mt][1] = __builtin_amdgcn_mfma_f32_16x16x32_bf16(Ahi[mt][kta], bl1, acc[mt][1], 0, 0, 0);
          acc[mt][2] = __builtin_amdgcn_mfma_f32_16x16x32_bf16(Ahi[mt][kta], bl2, acc[mt][2], 0, 0, 0);
          acc[mt][3] = __builtin_amdgcn_mfma_f32_16x16x32_bf16(Ahi[mt][kta], bl3, acc[mt][3], 0, 0, 0);
        }
      }
      // ---- two-phase cross-wave reduce via LDS ----
      float* hcur = xp + (size_t)s * HB;
      #pragma unroll
      for (int mt = 0; mt < 2; mt++) {
        #pragma unroll
        for (int i = 0; i < 4; i++)
          *(f32x4*)&red[(((w * 4 + i) * 64) + lane) * 4] = acc[mt][i];
        __syncthreads();
        #pragma unroll
        for (int rep = 0; rep < 2; rep++) {
          const int j = jA + rep * 8, b = bA;
          const int nt = b >> 4, lc = (j >> 2) * 16 + (b & 15), reg = j & 3;
          float sum = 0.f;
          #pragma unroll
          for (int ww = 0; ww < 8; ww++)
            sum += red[(((ww * 4 + nt) * 64) + lc) * 4 + reg];
          float v = tanhf(xc[mt * 2 + rep] + sum);
          // fp32 h published coherently (workers on other XCDs consume it)
          __hip_atomic_store(&hcur[xia[mt * 2 + rep]], v,
                             __ATOMIC_RELAXED, __HIP_MEMORY_SCOPE_AGENT);
          hbuf[(mt * 16 + j) * 64 + b] = v;
        }
        __syncthreads();
      }
      // ---- coalesced frag publish: 256 threads x (2+2) u64 sc1 stores ----
      if (t < 256) {
        const int jg = t >> 6, b = t & 63;
        const int k0 = j0 + jg * 8;           // 8 consecutive k, k0 % 8 == 0
        const int kt = k0 >> 5, qq = (k0 >> 3) & 3;
        const int nt = b >> 4, ln = qq * 16 + (b & 15);
        const size_t fb = ((size_t)((kt * 4 + nt) * 64 + ln)) * 8;
        unsigned hu[8], lu[8];
        #pragma unroll
        for (int jj = 0; jj < 8; jj++) {
          float v = hbuf[(jg * 8 + jj) * 64 + b];
          __bf16 hh = (__bf16)v;
          __bf16 ll = (__bf16)(v - (float)hh);
          hu[jj] = (unsigned)__builtin_bit_cast(unsigned short, hh);
          lu[jj] = (unsigned)__builtin_bit_cast(unsigned short, ll);
        }
        u64 hw0 = (u64)hu[0] | ((u64)hu[1] << 16) | ((u64)hu[2] << 32) | ((u64)hu[3] << 48);
        u64 hw1 = (u64)hu[4] | ((u64)hu[5] << 16) | ((u64)hu[6] << 32) | ((u64)hu[7] << 48);
        u64 lw0 = (u64)lu[0] | ((u64)lu[1] << 16) | ((u64)lu[2] << 32) | ((u64)lu[3] << 48);
        u64 lw1 = (u64)lu[4] | ((u64)lu[5] << 16) | ((u64)lu[6] << 32) | ((u64)lu[7] << 48);
        __hip_atomic_store((u64*)(wrh + fb) + 0, hw0, __ATOMIC_RELAXED, __HIP_MEMORY_SCOPE_AGENT);
        __hip_atomic_store((u64*)(wrh + fb) + 1, hw1, __ATOMIC_RELAXED, __HIP_MEMORY_SCOPE_AGENT);
        __hip_atomic_store((u64*)(wrl + fb) + 0, lw0, __ATOMIC_RELAXED, __HIP_MEMORY_SCOPE_AGENT);
        __hip_atomic_store((u64*)(wrl + fb) + 1, lw1, __ATOMIC_RELAXED, __HIP_MEMORY_SCOPE_AGENT);
      }
      __syncthreads();   // drains vmcnt -> all sc1 stores at IF$ before flag
      if (t == 0)
        __hip_atomic_store(&bar[blockIdx.x], (unsigned)(s + 1),
                           __ATOMIC_RELAXED, __HIP_MEMORY_SCOPE_AGENT);
      const int sn = s + 1;
      const float* xpn = xp + (size_t)sn * HB;
      if (t >= 64) {
        // waves 1..7: gated prefetch of next xp slice into regs
        if (sn < S_) {
          while (__hip_atomic_load(&incnt[sn], __ATOMIC_RELAXED,
                                   __HIP_MEMORY_SCOPE_AGENT) < NPROD_PER_S) {
            if (--budget < 0) break;
            __builtin_amdgcn_s_sleep(1);
          }
          asm volatile("" ::: "memory");
          #pragma unroll
          for (int p = 0; p < 4; p++) xc[p] = xpn[xia[p]];
        }
      } else {
        // acquire fence EARLY in poll window: buffer_inv overlaps the wait;
        // double buffering keeps stale-line refill impossible before use.
        __builtin_amdgcn_fence(__ATOMIC_ACQUIRE, "agent");
        if (sn < S_) {
          while (__hip_atomic_load(&incnt[sn], __ATOMIC_RELAXED,
                                   __HIP_MEMORY_SCOPE_AGENT) < NPROD_PER_S) {
            if (--budget < 0) break;
            __builtin_amdgcn_s_sleep(1);
          }
          asm volatile("" ::: "memory");
          #pragma unroll
          for (int p = 0; p < 4; p++) xc[p] = xpn[xia[p]];
        }
        if (lane < SCAN_NBLK) {
          const unsigned need = (unsigned)sn;
          while (__hip_atomic_load(&bar[lane], __ATOMIC_RELAXED,
                                   __HIP_MEMORY_SCOPE_AGENT) < need) {
            if (--budget < 0) break;
            __builtin_amdgcn_s_sleep(1);
          }
        }
        if (t == 0 && blockIdx.x == 0)
          __hip_atomic_store(dn, (unsigned)sn,
                             __ATOMIC_RELAXED, __HIP_MEMORY_SCOPE_AGENT);
      }
      __syncthreads();
      // swap double buffers
      const unsigned short* th = rdh; rdh = wrh; wrh = (unsigned short*)th;
      const unsigned short* tl = rdl; rdl = wrl; wrl = (unsigned short*)tl;
    }
  } else if (blockIdx.x < SCAN_NBLK + PROD_NBLK) {
    // ======================== INPROJ PRODUCERS ========================
    // item = s*8 + htile(128): xp[s][h][b] = sum_i x[b][s][i]*Wih[h][i]+bih+bhh
    float* As = sh;              // [128][36] Wih tile (h x k)
    float* Bs = sh + 128 * 36;   // [32][72]  x tile   (k x b)
    const int pid = blockIdx.x - SCAN_NBLK;
    const int tx = t & 15, ty = t >> 4;        // b-quad, h-quad (32 rows)
    const int bS = t >> 3, c4S = (t & 7) * 4;  // Bs staging coords
    for (int item = pid; item < S_ * 8; item += PROD_NBLK) {
      const int s = item >> 3, h00 = (item & 7) << 7;
      float acc[4][4] = {};
      for (int k0 = 0; k0 < I_; k0 += 32) {
        #pragma unroll
        for (int L = 0; L < 2; L++) {
          int f = L * 512 + t;
          int row = f >> 3, c4 = (f & 7) * 4;
          float4 v = *(const float4*)&Wih[(size_t)(h00 + row) * I_ + k0 + c4];
          *(float4*)&As[row * 36 + c4] = v;
        }
        {
          float4 v = *(const float4*)&x[(size_t)bS * (S_ * I_) + (size_t)s * I_ + k0 + c4S];
          Bs[(c4S + 0) * 72 + bS] = v.x;
          Bs[(c4S + 1) * 72 + bS] = v.y;
          Bs[(c4S + 2) * 72 + bS] = v.z;
          Bs[(c4S + 3) * 72 + bS] = v.w;
        }
        __syncthreads();
        #pragma unroll
        for (int k = 0; k < 32; k += 4) {
          float4 a[4], bq[4];
          #pragma unroll
          for (int r = 0; r < 4; r++) a[r] = *(const float4*)&As[(ty * 4 + r) * 36 + k];
          #pragma unroll
          for (int kk = 0; kk < 4; kk++) bq[kk] = *(const float4*)&Bs[(k + kk) * 72 + tx * 4];
          #pragma unroll
          for (int kk = 0; kk < 4; kk++)
            #pragma unroll
            for (int r = 0; r < 4; r++)
              #pragma unroll
              for (int c = 0; c < 4; c++)
                acc[r][c] += ((const float*)&a[r])[kk] * ((const float*)&bq[kk])[c];
        }
        __syncthreads();
      }
      #pragma unroll
      for (int r = 0; r < 4; r++) {
        const int h = h00 + ty * 4 + r;
        const float bias = bih[h] + bhh[h];
        float2 p0 = {acc[r][0] + bias, acc[r][1] + bias};
        float2 p1 = {acc[r][2] + bias, acc[r][3] + bias};
        u64* dst = (u64*)&xp[(size_t)s * HB + (size_t)h * 64 + tx * 4];
        __hip_atomic_store(dst + 0, __builtin_bit_cast(u64, p0),
                           __ATOMIC_RELAXED, __HIP_MEMORY_SCOPE_AGENT);
        __hip_atomic_store(dst + 1, __builtin_bit_cast(u64, p1),
                           __ATOMIC_RELAXED, __HIP_MEMORY_SCOPE_AGENT);
      }
      __syncthreads();   // drains vmcnt in every wave -> stores at IF$
      if (t == 0)
        __hip_atomic_fetch_add(&incnt[s], 1u,
                               __ATOMIC_RELAXED, __HIP_MEMORY_SCOPE_AGENT);
    }
  } else {
    // ======================== OUTPROJ WORKERS ========================
    // item = s*4 + otile(128): out[b][s][o] = sum_h hs[s][h][b]*Who[o][h]+bho
    float* As = sh;              // [32][68]  hs tile  (k x b)
    float* Bs = sh + 32 * 68;    // [32][132] Who tile (k x o)
    const int wid = blockIdx.x - SCAN_NBLK - PROD_NBLK;
    const int tx = t & 31, ty = t >> 5;          // o-quad (32), b-quad (16)
    const int kkA = t >> 4, b4 = (t & 15) * 4;   // As staging coords
    for (int item = wid; item < S_ * 4; item += WORK_NBLK) {
      const int s = item >> 2, o0 = (item & 3) << 7;
      if (t == 0) {
        const unsigned need = (unsigned)(s + 1);
        while (__hip_atomic_load(dn, __ATOMIC_RELAXED,
                                 __HIP_MEMORY_SCOPE_AGENT) < need) {
          if (--budget < 0) break;
          __builtin_amdgcn_s_sleep(8);
        }
      }
      __syncthreads();
      const float* hsS = xp + (size_t)s * HB;
      float acc[4][4] = {};
      for (int k0 = 0; k0 < H_; k0 += 32) {
        // hs via agent-scope u64 loads: coherent from IF$, no cache inv needed
        const u64* hp = (const u64*)&hsS[(size_t)(k0 + kkA) * 64 + b4];
        u64 w0 = __hip_atomic_load(hp + 0, __ATOMIC_RELAXED, __HIP_MEMORY_SCOPE_AGENT);
        u64 w1 = __hip_atomic_load(hp + 1, __ATOMIC_RELAXED, __HIP_MEMORY_SCOPE_AGENT);
        *(float2*)&As[kkA * 68 + b4 + 0] = __builtin_bit_cast(float2, w0);
        *(float2*)&As[kkA * 68 + b4 + 2] = __builtin_bit_cast(float2, w1);
        #pragma unroll
        for (int L = 0; L < 2; L++) {
          int f = L * 512 + t;
          int row = f >> 3, c4 = (f & 7) * 4;    // row in [0,128) = o offset
          float4 v = *(const float4*)&Who[(size_t)(o0 + row) * H_ + k0 + c4];
          Bs[(c4 + 0) * 132 + row] = v.x;
          Bs[(c4 + 1) * 132 + row] = v.y;
          Bs[(c4 + 2) * 132 + row] = v.z;
          Bs[(c4 + 3) * 132 + row] = v.w;
        }
        __syncthreads();
        #pragma unroll
        for (int k = 0; k < 32; k++) {
          float4 a4 = *(const float4*)&As[k * 68 + ty * 4];
          float4 bq = *(const float4*)&Bs[k * 132 + tx * 4];
          #pragma unroll
          for (int r = 0; r < 4; r++)
            #pragma unroll
            for (int c = 0; c < 4; c++)
              acc[r][c] += ((const float*)&a4)[r] * ((const float*)&bq)[c];
        }
        __syncthreads();
      }
      #pragma unroll
      for (int r = 0; r < 4; r++) {
        const int b = ty * 4 + r;
        float4 o4;
        o4.x = acc[r][0] + bho[o0 + tx * 4 + 0];
        o4.y = acc[r][1] + bho[o0 + tx * 4 + 1];
        o4.z = acc[r][2] + bho[o0 + tx * 4 + 2];
        o4.w = acc[r][3] + bho[o0 + tx * 4 + 3];
        *(float4*)&out[(size_t)b * (S_ * O_) + (size_t)s * O_ + o0 + tx * 4] = o4;
      }
    }
  }
}

// last hidden: (H,B) slice -> out (B,H)
__global__ void k_lasth(const float* __restrict__ hlast, float* __restrict__ out) {
  int idx = blockIdx.x * 256 + threadIdx.x;  // 65536 total
  int b = idx >> 10, h = idx & 1023;
  out[idx] = hlast[h * 64 + b];
}

extern "C" void kernel_launch(void* const* d_in, const int* in_sizes, int n_in,
                              void* d_out, int out_size, void* d_ws, size_t ws_size,
                              hipStream_t stream) {
  const float* x    = (const float*)d_in[0];
  const float* h0   = (const float*)d_in[1];
  const float* Wih  = (const float*)d_in[2];
  const float* bih  = (const float*)d_in[3];
  const float* Whh  = (const float*)d_in[4];
  const float* bhh  = (const float*)d_in[5];
  const float* Who  = (const float*)d_in[6];
  const float* bho  = (const float*)d_in[7];
  float* out = (float*)d_out;

  // ws: xp/hs (S,H,B) fp32 = 268.4 MB | 4 frag arrays 128 KB | counters 8 KB
  float* xp = (float*)d_ws;
  unsigned short* hh0 = (unsigned short*)(xp + (size_t)S_ * HB);
  unsigned short* hl0 = hh0 + HB;
  unsigned short* hh1 = hl0 + HB;
  unsigned short* hl1 = hh1 + HB;
  unsigned* bar = (unsigned*)(hl1 + HB);   // flags | done(+128) | incnt(+256)

  hipMemsetAsync(bar, 0, 8192, stream);
  k_hfrag0<<<256, 256, 0, stream>>>(h0, hh0, hl0);

  void* args[] = {(void*)&Whh, (void*)&xp, (void*)&hh0, (void*)&hl0,
                  (void*)&hh1, (void*)&hl1, (void*)&bar,
                  (void*)&Who, (void*)&bho, (void*)&out,
                  (void*)&x, (void*)&Wih, (void*)&bih, (void*)&bhh};
  hipLaunchCooperativeKernel((const void*)k_fused,
                             dim3(SCAN_NBLK + PROD_NBLK + WORK_NBLK), dim3(NTHR),
                             args, 0, stream);

  k_lasth<<<256, 256, 0, stream>>>(xp + (size_t)(S_ - 1) * HB, out + (size_t)B_ * S_ * O_);
}